// Round 6
// baseline (166.276 us; speedup 1.0000x reference)
//
#include <hip/hip_runtime.h>
#include <hip/hip_bf16.h>

#define NPIX (1 << 20)
#define HDIM 1024
#define FRAG_PER_IMG 131072
#define NB_FRAG 64
#define RBIT 0x40000000

// ============ global union-find with slot-encoded roots ============
// P[px] for masked px: parent pixel index (strictly smaller), or RBIT|slot
// if px is a component root. Parents only decrease -> acyclic; stale reads
// benign (extra hops, never wrong connectivity).
__device__ __forceinline__ int find_root_g(int* P, int x) {
    for (;;) {
        int v = P[x];
        if ((v & RBIT) || v == x) return x;
        int vp = P[v];
        if ((vp & RBIT) || vp == v) return v;
        P[x] = vp;   // path halving, benign race
        x = vp;
    }
}

__device__ __forceinline__ void unite_g(int* P, int a, int b) {
    int ra = find_root_g(P, a);
    int rb = find_root_g(P, b);
    while (ra != rb) {
        if (ra < rb) { int t = ra; ra = rb; rb = t; }   // ra = larger pixel
        int exp = P[ra];
        if ((exp & RBIT) || exp == ra) {
            int old = atomicCAS(&P[ra], exp, rb);
            if (old == exp) return;
        }
        ra = find_root_g(P, ra);
        rb = find_root_g(P, rb);
    }
}

// ============ LDS union-find over run nodes (id = row*16 + k) ============
__device__ __forceinline__ int find_r(int* R, int n) {
    int p = R[n];
    while (p != n) {
        int gp = R[p];
        if (gp == p) return p;
        R[n] = gp;   // compression, benign race
        n = gp;
        p = R[n];
    }
    return n;
}

__device__ __forceinline__ void unite_r(int* R, int a, int b) {
    a = find_r(R, a); b = find_r(R, b);
    while (a != b) {
        if (a < b) { int t = a; a = b; b = t; }
        int old = atomicCAS(&R[a], a, b);
        if (old == a) return;
        a = find_r(R, old); b = find_r(R, b);
    }
}

// ============ phase A: 4 tiles per 256-thread block, one tile per WAVE ====
// lane l: tile row r=l>>1, half h=l&1 (16 px). Waves are independent; the
// block barriers are symmetric (every wave runs the same phase schedule).
__global__ __launch_bounds__(256) void local_k(
        const float4* __restrict__ pred4, const float4* __restrict__ targ4,
        int* __restrict__ P, unsigned* __restrict__ mbits,
        int* __restrict__ fragRoot, float2* __restrict__ fragSums,
        int* __restrict__ fragCnt, int fragCap) {
    int wid = threadIdx.x >> 6;
    int l   = threadIdx.x & 63;
    int tile = blockIdx.x * 4 + wid;
    int img = tile >> 10;
    int ty = (tile >> 5) & 31, tx = tile & 31;
    int r = l >> 1, h = l & 1;

    __shared__ unsigned s_st[4][32];
    __shared__ int s_ruf[4][512];
    __shared__ float s_i[4][512], s_u[4][512];
    int*   ruf = &s_ruf[wid][0];
    float* si  = &s_i[wid][0];
    float* su  = &s_u[wid][0];

    int rowg = img * HDIM + ty * 32 + r;
    int qb = rowg * 256 + tx * 8 + h * 4;

    float sv[16], iv[16];
    unsigned hm = 0;
    #pragma unroll
    for (int q = 0; q < 4; ++q) {
        float4 P4 = pred4[qb + q];
        float4 T4 = targ4[qb + q];
        float s0 = P4.x + T4.x, s1 = P4.y + T4.y, s2 = P4.z + T4.z, s3 = P4.w + T4.w;
        sv[q*4+0] = s0; sv[q*4+1] = s1; sv[q*4+2] = s2; sv[q*4+3] = s3;
        iv[q*4+0] = P4.x * T4.x; iv[q*4+1] = P4.y * T4.y;
        iv[q*4+2] = P4.z * T4.z; iv[q*4+3] = P4.w * T4.w;
        if (s0 > 0.f) hm |= 1u << (q*4+0);
        if (s1 > 0.f) hm |= 1u << (q*4+1);
        if (s2 > 0.f) hm |= 1u << (q*4+2);
        if (s3 > 0.f) hm |= 1u << (q*4+3);
    }
    unsigned m = hm << (h * 16);
    m |= __shfl_xor(m, 1);                 // full 32-bit row mask on both lanes
    bool active = (__ballot(m != 0) != 0ull);
    unsigned st = m & ~(m << 1);           // full-row run starts
    if (h == 0) mbits[rowg * 32 + tx] = m;

    bool strad = false; int ridS = -2; float fi = 0.f, fu = 0.f;
    if (active) {
        #pragma unroll
        for (int k = 0; k < 8; ++k) ruf[l * 8 + k] = l * 8 + k;
        if (h == 0) s_st[wid][r] = st;
        // ---- P3a: per-run sums, exclusive plain stores ----
        strad = (h == 1) && ((m >> 15) & 1) && ((m >> 16) & 1);
        ridS = strad ? (__popc(st & 0x1FFFFu) - 1) : -2;
        int cur = -1; float ai = 0.f, au = 0.f;
        #pragma unroll
        for (int j = 0; j < 16; ++j) {
            if ((hm >> j) & 1) {
                int x = h * 16 + j;
                int rid = __popc(st & ((2u << x) - 1)) - 1;
                if (rid != cur) {
                    if (cur >= 0) {
                        if (cur == ridS) { fi = ai; fu = au; }
                        else { si[r*16+cur] = ai; su[r*16+cur] = au; }
                    }
                    cur = rid; ai = 0.f; au = 0.f;
                }
                ai += iv[j]; au += sv[j];
            }
        }
        if (cur >= 0) {
            if (cur == ridS) { fi = ai; fu = au; }
            else { si[r*16+cur] = ai; su[r*16+cur] = au; }
        }
    }
    __syncthreads();
    if (active) {
        // ---- P3b: fold straddler partial (exclusive RMW) ----
        if (strad) { si[r*16+ridS] += fi; su[r*16+ridS] += fu; }
        // ---- P4: vertical run unions, lane pair per row boundary ----
        int bsrc = (l & ~1) + 2; if (bsrc > 63) bsrc = 63;
        unsigned ma = __shfl(m, l & ~1);
        unsigned mb = __shfl(m, bsrc);
        if (l < 62) {
            int rr = l >> 1;
            unsigned sta = ma & ~(ma << 1);
            unsigned stb = mb & ~(mb << 1);
            unsigned o = ma & mb;
            unsigned os = o & ~(o << 1);
            os &= h ? 0xFFFF0000u : 0x0000FFFFu;
            while (os) {
                int x = __ffs(os) - 1; os &= os - 1;
                unsigned below = (2u << x) - 1;
                unite_r(ruf, rr * 16 + __popc(sta & below) - 1,
                             (rr + 1) * 16 + __popc(stb & below) - 1);
            }
        }
    }
    __syncthreads();
    // ---- P5: flatten to depth<=1 + fold run sums into roots ----
    unsigned strow8[8]; int root8[8]; bool valid8[8];
    if (active) {
        #pragma unroll
        for (int k = 0; k < 8; ++k) {
            int n = l * 8 + k;
            unsigned strow = s_st[wid][n >> 4];
            strow8[k] = strow;
            bool v = (n & 15) < __popc(strow);
            valid8[k] = v;
            root8[k] = n;
            if (v) {
                int root = find_r(ruf, n);
                root8[k] = root;
                if (root != n) {
                    float a = si[n], b = su[n];
                    ruf[n] = root;
                    atomicAdd(&si[root], a);
                    atomicAdd(&su[root], b);
                }
            }
        }
    }
    __syncthreads();
    // ---- P7: enumerate root runs -> slots; repurpose si/su as gr/tag ----
    if (active) {
        bool isroot[8]; int mycnt = 0;
        #pragma unroll
        for (int k = 0; k < 8; ++k) {
            bool rt = valid8[k] && (root8[k] == (l * 8 + k));
            isroot[k] = rt; mycnt += rt;
        }
        int inc = mycnt;
        #pragma unroll
        for (int d = 1; d < 64; d <<= 1) {
            int t = __shfl_up(inc, d);
            if (l >= d) inc += t;
        }
        int total = __shfl(inc, 63);
        int base = 0;
        if (l == 63 && total > 0) base = atomicAdd(fragCnt, total);
        base = __shfl(base, 63);
        int o = base + inc - mycnt;
        #pragma unroll
        for (int k = 0; k < 8; ++k) {
            if (isroot[k]) {
                int n = l * 8 + k;
                int row = n >> 4, k2 = n & 15;
                unsigned sm = strow8[k];
                for (int z = 0; z < k2; ++z) sm &= sm - 1;
                int rx = __ffs(sm) - 1;
                int gr = (img * HDIM + ty * 32 + row) * HDIM + tx * 32 + rx;
                int slot = o++;
                if (slot < fragCap) {
                    fragRoot[slot] = gr;
                    fragSums[slot] = make_float2(si[n], su[n]);
                }
                si[n] = __int_as_float(gr);          // root pixel gid
                su[n] = __int_as_float(RBIT | slot); // root tag
            }
        }
    }
    __syncthreads();
    // ---- P6: per-pixel parent quads via depth-1 lookup ----
    if (active) {
        int pbase0 = rowg * HDIM + tx * 32 + h * 16;
        int gr = 0, tag = 0; bool have = false;
        #pragma unroll
        for (int q = 0; q < 4; ++q) {
            int pv[4];
            unsigned qm = (hm >> (q * 4)) & 0xFu;
            #pragma unroll
            for (int j = 0; j < 4; ++j) {
                int jj = q * 4 + j;
                pv[j] = 0;
                if ((hm >> jj) & 1) {
                    int x = h * 16 + jj;
                    bool entry = (x == 0) || !((m >> (x - 1)) & 1);
                    if (entry || !have) {
                        int node = r * 16 + __popc(st & ((2u << x) - 1)) - 1;
                        int root = ruf[node];
                        gr  = __float_as_int(si[root]);
                        tag = __float_as_int(su[root]);
                        have = true;
                    }
                    pv[j] = (pbase0 + jj == gr) ? tag : gr;
                }
            }
            if (qm) *(int4*)(P + pbase0 + q * 4) = make_int4(pv[0], pv[1], pv[2], pv[3]);
        }
    }
}

// ============ phase B: boundary unions (63488 edges/image) ============
__global__ void bound_k(const unsigned* __restrict__ mbits, int* __restrict__ P) {
    int img = blockIdx.x / 248;
    int e = (blockIdx.x % 248) * 256 + threadIdx.x;
    int g1, g2;
    if (e < 31744) {            // vertical boundary: x = 32k+31 <-> x+1
        int k = e >> 10, y = e & 1023;
        unsigned w1 = mbits[(img * HDIM + y) * 32 + k];
        unsigned w2 = mbits[(img * HDIM + y) * 32 + k + 1];
        if (!(w1 >> 31) || !(w2 & 1)) return;
        g1 = img * NPIX + y * HDIM + k * 32 + 31;
        g2 = g1 + 1;
    } else {                    // horizontal boundary: y = 32k+31 <-> y+1
        int e2 = e - 31744;
        int k = e2 >> 10, x = e2 & 1023;
        int y = k * 32 + 31;
        unsigned w1 = mbits[(img * HDIM + y) * 32 + (x >> 5)];
        unsigned w2 = mbits[(img * HDIM + y + 1) * 32 + (x >> 5)];
        unsigned b = x & 31;
        if (!((w1 >> b) & 1) || !((w2 >> b) & 1)) return;
        g1 = img * NPIX + y * HDIM + x;
        g2 = g1 + HDIM;
    }
    unite_g(P, g1, g2);
}

// ============ phase C: fold donor fragments into final roots ============
__global__ void merge_frag_k(const int* __restrict__ fragRoot, const int* __restrict__ fragCnt,
                             int* __restrict__ P, float* __restrict__ fragSums, int fragCap) {
    int n = fragCnt[0]; if (n > fragCap) n = fragCap;
    for (int i = blockIdx.x * blockDim.x + threadIdx.x; i < n;
         i += gridDim.x * blockDim.x) {
        int r0 = fragRoot[i];
        int r = find_root_g(P, r0);
        if (r != r0) {
            int v = P[r];
            if (v & RBIT) {
                int s = v & (RBIT - 1);
                float2 d = ((const float2*)fragSums)[i];
                unsafeAtomicAdd(&fragSums[2 * s], d.x);
                unsafeAtomicAdd(&fragSums[2 * s + 1], d.y);
            }
        }
    }
}

// ============ phase D: dice over final roots, block partials ============
__global__ void dice_frag_k(const int* __restrict__ fragRoot, const int* __restrict__ fragCnt,
                            const int* __restrict__ P, const float2* __restrict__ fragSums,
                            float* __restrict__ partials, int b0, int B, int fragCap) {
    __shared__ float sb[8][2];
    if (threadIdx.x < 16) ((float*)sb)[threadIdx.x] = 0.f;
    __syncthreads();
    int n = fragCnt[0]; if (n > fragCap) n = fragCap;
    for (int i = blockIdx.x * blockDim.x + threadIdx.x; i < n;
         i += gridDim.x * blockDim.x) {
        int r0 = fragRoot[i];
        if (!(P[r0] & RBIT)) continue;   // not a final root
        float2 su = fragSums[i];
        float d = (2.f * su.x + 1e-6f) / (su.y + 1e-6f);
        int ci = r0 >> 20;               // chunk-local image
        atomicAdd(&sb[ci][0], d);
        atomicAdd(&sb[ci][1], 1.f);
    }
    __syncthreads();
    if (threadIdx.x < 16) {
        int ci = threadIdx.x >> 1, j = threadIdx.x & 1;
        int imgg = b0 + ci;
        if (imgg < B)
            partials[(blockIdx.x * B + imgg) * 2 + j] += ((float*)sb)[threadIdx.x];
    }
}

__global__ void zero_partials_k(float* __restrict__ p, int n, int* __restrict__ fragCnt) {
    int i = blockIdx.x * blockDim.x + threadIdx.x;
    if (i < n) p[i] = 0.f;
    if (i == 0) fragCnt[0] = 0;
}
__global__ void zero_frag_k(int* __restrict__ fragCnt) {
    if (threadIdx.x == 0) fragCnt[0] = 0;
}

__global__ void final_k(const float* __restrict__ partials, float* __restrict__ out, int B) {
    __shared__ float sb[128][2];
    int t = threadIdx.x;
    if (t < 2 * B) {
        int img = t >> 1, j = t & 1;
        float a = 0.f;
        for (int bkt = 0; bkt < NB_FRAG; ++bkt) a += partials[(bkt * B + img) * 2 + j];
        sb[img][j] = a;
    }
    __syncthreads();
    if (t == 0) {
        float acc = 0.f;
        for (int img = 0; img < B; ++img) {
            float s = sb[img][0], nn = sb[img][1];
            acc += (nn > 0.f) ? (1.f - s / nn) : 1.f;
        }
        out[0] = acc / (float)B;
    }
}

// ============ launch ============
extern "C" void kernel_launch(void* const* d_in, const int* in_sizes, int n_in,
                              void* d_out, int out_size, void* d_ws, size_t ws_size,
                              hipStream_t stream) {
    const float* pred = (const float*)d_in[0];
    const float* targ = (const float*)d_in[1];
    float* out = (float*)d_out;
    int B = in_sizes[0] / NPIX;
    if (B < 1) B = 1;

    char* ws = (char*)d_ws;
    size_t off = 0;
    float* partials = (float*)ws;
    off += ((size_t)NB_FRAG * B * 2 * sizeof(float) + 255) & ~(size_t)255;
    int* fragCnt = (int*)(ws + off);
    off += 256;
    size_t fixed = off;

    const size_t perImg = (size_t)NPIX * 4 + (size_t)HDIM * 32 * 4
                        + (size_t)FRAG_PER_IMG * 4 + (size_t)FRAG_PER_IMG * 8;
    int maxC = 1;
    if (ws_size > fixed + perImg) {
        size_t m = (ws_size - fixed) / perImg;
        maxC = (int)(m < (size_t)B ? m : (size_t)B);
        if (maxC < 1) maxC = 1;
        if (maxC > 8) maxC = 8;
    }
    int*      P        = (int*)     (ws + off); off += (size_t)maxC * NPIX * 4;
    unsigned* mbits    = (unsigned*)(ws + off); off += (size_t)maxC * HDIM * 32 * 4;
    int*      fragRoot = (int*)     (ws + off); off += (size_t)maxC * FRAG_PER_IMG * 4;
    float2*   fragSums = (float2*)  (ws + off);

    zero_partials_k<<<(NB_FRAG * B * 2 + 255) / 256, 256, 0, stream>>>(
        partials, NB_FRAG * B * 2, fragCnt);

    for (int b0 = 0; b0 < B; b0 += maxC) {
        int C = (B - b0 < maxC) ? (B - b0) : maxC;
        const float* pc = pred + (size_t)b0 * NPIX;
        const float* tc = targ + (size_t)b0 * NPIX;
        int fragCap = C * FRAG_PER_IMG;
        if (b0 > 0) zero_frag_k<<<1, 64, 0, stream>>>(fragCnt);
        local_k<<<C * 256, 256, 0, stream>>>((const float4*)pc, (const float4*)tc,
                                             P, mbits, fragRoot, fragSums, fragCnt, fragCap);
        bound_k<<<C * 248, 256, 0, stream>>>(mbits, P);
        merge_frag_k<<<128, 256, 0, stream>>>(fragRoot, fragCnt, P, (float*)fragSums, fragCap);
        dice_frag_k<<<NB_FRAG, 256, 0, stream>>>(fragRoot, fragCnt, P, fragSums,
                                                 partials, b0, B, fragCap);
    }

    final_k<<<1, 256, 0, stream>>>(partials, out, B);
}

// Round 7
// 150.610 us; speedup vs baseline: 1.1040x; 1.1040x over previous
//
#include <hip/hip_runtime.h>
#include <hip/hip_bf16.h>

#define NPIX (1 << 20)
#define HDIM 1024
#define FRAG_PER_IMG 131072
#define NB_FRAG 64

#define WBAR() __builtin_amdgcn_wave_barrier()

// ============ slot-level union-find (global, union-by-min) ============
// F[i] <= i invariant; parents only decrease; stale reads benign.
__device__ __forceinline__ int find_f(int* F, int x) {
    for (;;) {
        int p = F[x];
        if (p == x) return x;
        int gp = F[p];
        if (gp == p) return p;
        F[x] = gp;   // path halving, benign race
        x = gp;
    }
}
__device__ __forceinline__ void unite_f(int* F, int a, int b) {
    a = find_f(F, a); b = find_f(F, b);
    while (a != b) {
        if (a < b) { int t = a; a = b; b = t; }
        int old = atomicCAS(&F[a], a, b);
        if (old == a) return;
        a = find_f(F, old); b = find_f(F, b);
    }
}

// ============ LDS union-find over run nodes (id = row*16 + k) ============
__device__ __forceinline__ int find_r(int* R, int n) {
    int p = R[n];
    while (p != n) {
        int gp = R[p];
        if (gp == p) return p;
        R[n] = gp;   // compression, benign race
        n = gp;
        p = R[n];
    }
    return n;
}
__device__ __forceinline__ void unite_r(int* R, int a, int b) {
    a = find_r(R, a); b = find_r(R, b);
    while (a != b) {
        if (a < b) { int t = a; a = b; b = t; }
        int old = atomicCAS(&R[a], a, b);
        if (old == a) return;
        a = find_r(R, old); b = find_r(R, b);
    }
}

// ============ phase A: 4 tiles per block, one tile per WAVE, no barriers ==
// Per tile output: edge maps (slot id per boundary px, -1 unmasked) and
// fragment records (img, sums). LDS is wave-private -> no __syncthreads.
__global__ __launch_bounds__(256) void local_k(
        const float4* __restrict__ pred4, const float4* __restrict__ targ4,
        int* __restrict__ edges, int* __restrict__ F,
        int* __restrict__ fragImg, float2* __restrict__ fragSums,
        int* __restrict__ fragCnt, int fragCap) {
    int wid = threadIdx.x >> 6;
    int l   = threadIdx.x & 63;
    int tile = blockIdx.x * 4 + wid;       // chunk-local
    int img = tile >> 10;
    int ty = (tile >> 5) & 31, tx = tile & 31;
    int r = l >> 1, h = l & 1;

    __shared__ int s_ruf[4][512];
    __shared__ float s_i[4][512], s_u[4][512];
    int*   ruf = &s_ruf[wid][0];
    float* si  = &s_i[wid][0];
    float* su  = &s_u[wid][0];

    int rowg = img * HDIM + ty * 32 + r;
    int qb = rowg * 256 + tx * 8 + h * 4;
    int ebase = tile * 128;

    float sv[16], iv[16];
    unsigned hm = 0;
    #pragma unroll
    for (int q = 0; q < 4; ++q) {
        float4 P4 = pred4[qb + q];
        float4 T4 = targ4[qb + q];
        float s0 = P4.x + T4.x, s1 = P4.y + T4.y, s2 = P4.z + T4.z, s3 = P4.w + T4.w;
        sv[q*4+0] = s0; sv[q*4+1] = s1; sv[q*4+2] = s2; sv[q*4+3] = s3;
        iv[q*4+0] = P4.x * T4.x; iv[q*4+1] = P4.y * T4.y;
        iv[q*4+2] = P4.z * T4.z; iv[q*4+3] = P4.w * T4.w;
        if (s0 > 0.f) hm |= 1u << (q*4+0);
        if (s1 > 0.f) hm |= 1u << (q*4+1);
        if (s2 > 0.f) hm |= 1u << (q*4+2);
        if (s3 > 0.f) hm |= 1u << (q*4+3);
    }
    unsigned m = hm << (h * 16);
    m |= __shfl_xor(m, 1);                 // full 32-bit row mask on both lanes
    unsigned st = m & ~(m << 1);           // run starts
    int nrun = __popc(st);
    bool active = (__ballot(m != 0) != 0ull);

    if (!active) {                          // empty tile: -1 edges only
        int4 neg = make_int4(-1, -1, -1, -1);
        if (h == 0) edges[ebase + r] = -1;
        else        edges[ebase + 32 + r] = -1;
        if (r == 0)  { *(int4*)(edges + ebase + 64 + h*16) = neg;
                       *(int4*)(edges + ebase + 64 + h*16 + 4) = neg;
                       *(int4*)(edges + ebase + 64 + h*16 + 8) = neg;
                       *(int4*)(edges + ebase + 64 + h*16 + 12) = neg; }
        if (r == 31) { *(int4*)(edges + ebase + 96 + h*16) = neg;
                       *(int4*)(edges + ebase + 96 + h*16 + 4) = neg;
                       *(int4*)(edges + ebase + 96 + h*16 + 8) = neg;
                       *(int4*)(edges + ebase + 96 + h*16 + 12) = neg; }
        return;
    }

    #pragma unroll
    for (int k = 0; k < 8; ++k) ruf[l * 8 + k] = l * 8 + k;

    // ---- P3a: per-run sums, incremental rid, exclusive plain stores ----
    bool strad = (h == 1) && ((m >> 15) & 1) && ((m >> 16) & 1);
    int ridS = strad ? (__popc(st & 0xFFFFu) - 1) : -2;
    int rid = h ? (__popc(st & 0xFFFFu) - 1) : -1;
    bool in = strad;
    float fi = 0.f, fu = 0.f, ai = 0.f, au = 0.f;
    #pragma unroll
    for (int j = 0; j < 16; ++j) {
        if ((hm >> j) & 1) {
            int x = h * 16 + j;
            if ((st >> x) & 1) {
                if (in) {
                    if (rid == ridS) { fi = ai; fu = au; }
                    else { si[r*16+rid] = ai; su[r*16+rid] = au; }
                }
                ++rid; ai = 0.f; au = 0.f; in = true;
            }
            ai += iv[j]; au += sv[j];
        }
    }
    if (in) {
        if (rid == ridS) { fi = ai; fu = au; }
        else { si[r*16+rid] = ai; su[r*16+rid] = au; }
    }
    WBAR();
    // ---- P3b: fold straddler partial (exclusive RMW; DS in-order/wave) ----
    if (strad) { si[r*16+ridS] += fi; su[r*16+ridS] += fu; }
    WBAR();
    // ---- P4: vertical run unions, lane pair per row boundary ----
    {
        int bsrc = (l & ~1) + 2; if (bsrc > 63) bsrc = 63;
        unsigned mb = __shfl(m, bsrc);
        if (l < 62) {
            unsigned stb = mb & ~(mb << 1);
            unsigned o = m & mb;
            unsigned os = o & ~(o << 1);
            os &= h ? 0xFFFF0000u : 0x0000FFFFu;
            while (os) {
                int x = __ffs(os) - 1; os &= os - 1;
                unsigned below = (2u << x) - 1;
                unite_r(ruf, r * 16 + __popc(st & below) - 1,
                             (r + 1) * 16 + __popc(stb & below) - 1);
            }
        }
    }
    WBAR();
    // ---- P5: flatten to depth<=1 + fold run sums into roots ----
    int root8[8]; bool valid8[8];
    #pragma unroll
    for (int k = 0; k < 8; ++k) {
        int n = l * 8 + k;                 // node in OWN row (r = l>>1)
        bool v = (n & 15) < nrun;
        valid8[k] = v; root8[k] = n;
        if (v) {
            int root = find_r(ruf, n);
            root8[k] = root;
            if (root != n) {
                float a = si[n], b = su[n];
                ruf[n] = root;
                atomicAdd(&si[root], a);
                atomicAdd(&su[root], b);
            }
        }
    }
    WBAR();
    // ---- P7: slot alloc (1 global atomic/wave); encode ~slot into ruf ----
    {
        bool isroot[8]; int mycnt = 0;
        #pragma unroll
        for (int k = 0; k < 8; ++k) {
            bool rt = valid8[k] && (root8[k] == l * 8 + k);
            isroot[k] = rt; mycnt += rt;
        }
        int inc = mycnt;
        #pragma unroll
        for (int d = 1; d < 64; d <<= 1) {
            int t = __shfl_up(inc, d);
            if (l >= d) inc += t;
        }
        int base = 0;
        if (l == 63) base = atomicAdd(fragCnt, inc);
        base = __shfl(base, 63);
        int o = base + inc - mycnt;
        #pragma unroll
        for (int k = 0; k < 8; ++k) {
            if (isroot[k]) {
                int n = l * 8 + k;
                int slot = o++;
                if (slot < fragCap) {
                    F[slot] = slot;
                    fragImg[slot] = img;
                    fragSums[slot] = make_float2(si[n], su[n]);
                    ruf[n] = ~slot;
                } else ruf[n] = ~0;
            }
        }
    }
    WBAR();
    // ---- edges: slot id per boundary pixel ----
    {
        int s = -1;
        if (h == 0) {
            if (m & 1u) { int v = ruf[r * 16]; s = (v < 0) ? ~v : ~ruf[v]; }
            edges[ebase + r] = s;
        } else {
            if (m >> 31) { int v = ruf[r * 16 + nrun - 1]; s = (v < 0) ? ~v : ~ruf[v]; }
            edges[ebase + 32 + r] = s;
        }
    }
    if (r == 0 || r == 31) {
        int eoff = ebase + (r == 0 ? 64 : 96);
        int nb = r * 16;
        int rid2 = h ? (__popc(st & 0xFFFFu) - 1) : -1;
        #pragma unroll
        for (int j = 0; j < 16; ++j) {
            int x = h * 16 + j;
            int s = -1;
            if ((hm >> j) & 1) {
                if ((st >> x) & 1) ++rid2;
                int v = ruf[nb + rid2];
                s = (v < 0) ? ~v : ~ruf[v];
            }
            edges[eoff + x] = s;
        }
    }
}

// ============ phase B: boundary slot unions (63488 edge checks/image) =====
__global__ void bound_k(const int* __restrict__ edges, int* __restrict__ F) {
    int img = blockIdx.x / 248;
    int e = (blockIdx.x % 248) * 256 + threadIdx.x;
    int sA, sB;
    if (e < 31744) {            // vertical boundary: tx=k <-> k+1, row y
        int k = e >> 10, y = e & 1023;
        int ty = y >> 5, rr = y & 31;
        int tileA = img * 1024 + ty * 32 + k;
        sA = edges[tileA * 128 + 32 + rr];        // R edge of A
        sB = edges[(tileA + 1) * 128 + rr];       // L edge of B
    } else {                    // horizontal boundary: tile-row k <-> k+1, col x
        int e2 = e - 31744;
        int k = e2 >> 10, x = e2 & 1023;
        int tileA = img * 1024 + k * 32 + (x >> 5);
        sA = edges[tileA * 128 + 96 + (x & 31)];  // B edge of upper
        sB = edges[(tileA + 32) * 128 + 64 + (x & 31)]; // T edge of lower
    }
    if (sA >= 0 && sB >= 0) unite_f(F, sA, sB);
}

// ============ phase C: fold donor fragments into final roots ============
__global__ void merge_frag_k(int* __restrict__ F, float* __restrict__ fragSums,
                             const int* __restrict__ fragCnt, int fragCap) {
    int n = fragCnt[0]; if (n > fragCap) n = fragCap;
    for (int i = blockIdx.x * blockDim.x + threadIdx.x; i < n;
         i += gridDim.x * blockDim.x) {
        int rt = find_f(F, i);
        if (rt != i) {
            float2 d = ((const float2*)fragSums)[i];
            unsafeAtomicAdd(&fragSums[2 * rt], d.x);
            unsafeAtomicAdd(&fragSums[2 * rt + 1], d.y);
        }
    }
}

// ============ phase D: dice over final roots, block partials ============
__global__ void dice_frag_k(const int* __restrict__ F, const int* __restrict__ fragImg,
                            const float2* __restrict__ fragSums,
                            const int* __restrict__ fragCnt,
                            float* __restrict__ partials, int b0, int B, int fragCap) {
    __shared__ float sb[8][2];
    if (threadIdx.x < 16) ((float*)sb)[threadIdx.x] = 0.f;
    __syncthreads();
    int n = fragCnt[0]; if (n > fragCap) n = fragCap;
    for (int i = blockIdx.x * blockDim.x + threadIdx.x; i < n;
         i += gridDim.x * blockDim.x) {
        if (F[i] != i) continue;             // not a final root
        float2 s2 = fragSums[i];
        float d = (2.f * s2.x + 1e-6f) / (s2.y + 1e-6f);
        int ci = fragImg[i];                 // chunk-local image
        atomicAdd(&sb[ci][0], d);
        atomicAdd(&sb[ci][1], 1.f);
    }
    __syncthreads();
    if (threadIdx.x < 16) {
        int ci = threadIdx.x >> 1, j = threadIdx.x & 1;
        int imgg = b0 + ci;
        if (imgg < B)
            partials[(blockIdx.x * B + imgg) * 2 + j] += ((float*)sb)[threadIdx.x];
    }
}

__global__ void zero_partials_k(float* __restrict__ p, int n, int* __restrict__ fragCnt) {
    int i = blockIdx.x * blockDim.x + threadIdx.x;
    if (i < n) p[i] = 0.f;
    if (i == 0) fragCnt[0] = 0;
}
__global__ void zero_frag_k(int* __restrict__ fragCnt) {
    if (threadIdx.x == 0) fragCnt[0] = 0;
}

__global__ void final_k(const float* __restrict__ partials, float* __restrict__ out, int B) {
    __shared__ float sb[128][2];
    int t = threadIdx.x;
    if (t < 2 * B) {
        int img = t >> 1, j = t & 1;
        float a = 0.f;
        for (int bkt = 0; bkt < NB_FRAG; ++bkt) a += partials[(bkt * B + img) * 2 + j];
        sb[img][j] = a;
    }
    __syncthreads();
    if (t == 0) {
        float acc = 0.f;
        for (int img = 0; img < B; ++img) {
            float s = sb[img][0], nn = sb[img][1];
            acc += (nn > 0.f) ? (1.f - s / nn) : 1.f;
        }
        out[0] = acc / (float)B;
    }
}

// ============ launch ============
extern "C" void kernel_launch(void* const* d_in, const int* in_sizes, int n_in,
                              void* d_out, int out_size, void* d_ws, size_t ws_size,
                              hipStream_t stream) {
    const float* pred = (const float*)d_in[0];
    const float* targ = (const float*)d_in[1];
    float* out = (float*)d_out;
    int B = in_sizes[0] / NPIX;
    if (B < 1) B = 1;

    char* ws = (char*)d_ws;
    size_t off = 0;
    float* partials = (float*)ws;
    off += ((size_t)NB_FRAG * B * 2 * sizeof(float) + 255) & ~(size_t)255;
    int* fragCnt = (int*)(ws + off);
    off += 256;
    size_t fixed = off;

    // per-image: edges 512KB + F 512KB + fragImg 512KB + fragSums 1MB = 2.5MB
    const size_t perImg = (size_t)1024 * 128 * 4 + (size_t)FRAG_PER_IMG * 4
                        + (size_t)FRAG_PER_IMG * 4 + (size_t)FRAG_PER_IMG * 8;
    int maxC = 1;
    if (ws_size > fixed + perImg) {
        size_t mm = (ws_size - fixed) / perImg;
        maxC = (int)(mm < (size_t)B ? mm : (size_t)B);
        if (maxC < 1) maxC = 1;
        if (maxC > 8) maxC = 8;
    }
    int*    edgesA   = (int*)   (ws + off); off += (size_t)maxC * 1024 * 128 * 4;
    int*    F        = (int*)   (ws + off); off += (size_t)maxC * FRAG_PER_IMG * 4;
    int*    fragImg  = (int*)   (ws + off); off += (size_t)maxC * FRAG_PER_IMG * 4;
    float2* fragSums = (float2*)(ws + off);

    zero_partials_k<<<(NB_FRAG * B * 2 + 255) / 256, 256, 0, stream>>>(
        partials, NB_FRAG * B * 2, fragCnt);

    for (int b0 = 0; b0 < B; b0 += maxC) {
        int C = (B - b0 < maxC) ? (B - b0) : maxC;
        const float* pc = pred + (size_t)b0 * NPIX;
        const float* tc = targ + (size_t)b0 * NPIX;
        int fragCap = C * FRAG_PER_IMG;
        if (b0 > 0) zero_frag_k<<<1, 64, 0, stream>>>(fragCnt);
        local_k<<<C * 256, 256, 0, stream>>>((const float4*)pc, (const float4*)tc,
                                             edgesA, F, fragImg, fragSums, fragCnt, fragCap);
        bound_k<<<C * 248, 256, 0, stream>>>(edgesA, F);
        merge_frag_k<<<128, 256, 0, stream>>>(F, (float*)fragSums, fragCnt, fragCap);
        dice_frag_k<<<NB_FRAG, 256, 0, stream>>>(F, fragImg, fragSums, fragCnt,
                                                 partials, b0, B, fragCap);
    }

    final_k<<<1, 256, 0, stream>>>(partials, out, B);
}

// Round 8
// 150.261 us; speedup vs baseline: 1.1066x; 1.0023x over previous
//
#include <hip/hip_runtime.h>
#include <hip/hip_bf16.h>

#define NPIX (1 << 20)
#define HDIM 1024
#define FRAG_PER_IMG 131072
#define NB_FRAG 64

#define WBAR() __builtin_amdgcn_wave_barrier()

// ============ slot-level union-find (global, union-by-min) ============
__device__ __forceinline__ int find_f(int* F, int x) {
    for (;;) {
        int p = F[x];
        if (p == x) return x;
        int gp = F[p];
        if (gp == p) return p;
        F[x] = gp;   // path halving, benign race
        x = gp;
    }
}
__device__ __forceinline__ void unite_f(int* F, int a, int b) {
    a = find_f(F, a); b = find_f(F, b);
    while (a != b) {
        if (a < b) { int t = a; a = b; b = t; }
        int old = atomicCAS(&F[a], a, b);
        if (old == a) return;
        a = find_f(F, old); b = find_f(F, b);
    }
}

// ============ LDS union-find over run nodes (id = row*16 + k) ============
__device__ __forceinline__ int find_r(int* R, int n) {
    int p = R[n];
    while (p != n) {
        int gp = R[p];
        if (gp == p) return p;
        R[n] = gp;
        n = gp;
        p = R[n];
    }
    return n;
}
__device__ __forceinline__ void unite_r(int* R, int a, int b) {
    a = find_r(R, a); b = find_r(R, b);
    while (a != b) {
        if (a < b) { int t = a; a = b; b = t; }
        int old = atomicCAS(&R[a], a, b);
        if (old == a) return;
        a = find_r(R, old); b = find_r(R, b);
    }
}

// ============ phase A: 4 tiles/block, one tile per WAVE, interleaved ======
__global__ __launch_bounds__(256) void local_k(
        const float4* __restrict__ pred4, const float4* __restrict__ targ4,
        int* __restrict__ edges, int* __restrict__ F,
        int* __restrict__ fragImg, float2* __restrict__ fragSums,
        int* __restrict__ fragCnt, int fragCap, int nwg) {
    int wid = threadIdx.x >> 6;
    int l   = threadIdx.x & 63;
    int tile = wid * nwg + blockIdx.x;     // interleaved: block mixes 4 distant tiles
    int img = tile >> 10;
    int ty = (tile >> 5) & 31, tx = tile & 31;
    int r = l >> 1, h = l & 1;

    __shared__ int s_ruf[4][512];
    __shared__ float s_i[4][512], s_u[4][512];
    int*   ruf = &s_ruf[wid][0];
    float* si  = &s_i[wid][0];
    float* su  = &s_u[wid][0];

    int rowg = img * HDIM + ty * 32 + r;
    int qb = rowg * 256 + tx * 8 + h * 4;
    int ebase = tile * 128;

    float sv[16], iv[16];
    unsigned hm = 0;
    #pragma unroll
    for (int q = 0; q < 4; ++q) {
        float4 P4 = pred4[qb + q];
        float4 T4 = targ4[qb + q];
        float s0 = P4.x + T4.x, s1 = P4.y + T4.y, s2 = P4.z + T4.z, s3 = P4.w + T4.w;
        sv[q*4+0] = s0; sv[q*4+1] = s1; sv[q*4+2] = s2; sv[q*4+3] = s3;
        iv[q*4+0] = P4.x * T4.x; iv[q*4+1] = P4.y * T4.y;
        iv[q*4+2] = P4.z * T4.z; iv[q*4+3] = P4.w * T4.w;
        if (s0 > 0.f) hm |= 1u << (q*4+0);
        if (s1 > 0.f) hm |= 1u << (q*4+1);
        if (s2 > 0.f) hm |= 1u << (q*4+2);
        if (s3 > 0.f) hm |= 1u << (q*4+3);
    }
    unsigned m = hm << (h * 16);
    m |= __shfl_xor(m, 1);                 // full 32-bit row mask on both lanes
    unsigned st = m & ~(m << 1);           // run starts
    int nrun = __popc(st);

    if (__ballot(m != 0) == 0ull) {        // empty tile: -1 edges, 2 stores/lane
        edges[ebase + l] = -1;             // L(0..31) | R(32..63)
        edges[ebase + 64 + l] = -1;        // T(64..95) | B(96..127)
        return;
    }

    #pragma unroll
    for (int k = 0; k < 8; ++k) ruf[l * 8 + k] = l * 8 + k;

    // ---- P3a: per-run sums; straddler partial passed in registers ----
    int nrun0 = __popc(st & 0xFFFFu);
    bool strad = ((m >> 15) & 1) && ((m >> 16) & 1);
    float ai = 0.f, au = 0.f, fi = 0.f, fu = 0.f;
    int rid = h ? (nrun0 - 1) : -1;
    bool in = false;
    #pragma unroll
    for (int j = 0; j < 16; ++j) {
        if ((hm >> j) & 1) {
            int x = h * 16 + j;
            if ((st >> x) & 1) {
                if (in) { si[r*16+rid] = ai; su[r*16+rid] = au; }
                ++rid; ai = 0.f; au = 0.f; in = true;
            }
            if (in) { ai += iv[j]; au += sv[j]; }
            else    { fi += iv[j]; fu += sv[j]; }   // leading continuation (h=1)
        }
    }
    float gi = __shfl_xor(fi, 1), gu = __shfl_xor(fu, 1);
    if (in) {
        if (h == 0 && strad) { ai += gi; au += gu; }
        si[r*16+rid] = ai; su[r*16+rid] = au;
    }
    WBAR();
    // ---- P4: vertical run unions, lane pair per row boundary ----
    {
        int bsrc = (l & ~1) + 2; if (bsrc > 63) bsrc = 63;
        unsigned mb = __shfl(m, bsrc);
        if (l < 62) {
            unsigned stb = mb & ~(mb << 1);
            unsigned o = m & mb;
            unsigned os = o & ~(o << 1);
            os &= h ? 0xFFFF0000u : 0x0000FFFFu;
            while (os) {
                int x = __ffs(os) - 1; os &= os - 1;
                unsigned below = (2u << x) - 1;
                unite_r(ruf, r * 16 + __popc(st & below) - 1,
                             (r + 1) * 16 + __popc(stb & below) - 1);
            }
        }
    }
    WBAR();
    // ---- P5: flatten + fold sums into roots (nodes interleaved across pair) ----
    int root8[8]; bool valid8[8];
    #pragma unroll
    for (int k = 0; k < 8; ++k) {
        int ridx = k * 2 + h;
        int n = r * 16 + ridx;
        bool v = ridx < nrun;
        valid8[k] = v; root8[k] = n;
        if (v) {
            int root = find_r(ruf, n);
            root8[k] = root;
            if (root != n) {
                float a = si[n], b = su[n];
                ruf[n] = root;
                atomicAdd(&si[root], a);
                atomicAdd(&su[root], b);
            }
        }
    }
    WBAR();
    // ---- P7: slot alloc (1 global atomic/wave); encode ~slot into ruf ----
    {
        bool isroot[8]; int mycnt = 0;
        #pragma unroll
        for (int k = 0; k < 8; ++k) {
            int n = r * 16 + k * 2 + h;
            bool rt = valid8[k] && (root8[k] == n);
            isroot[k] = rt; mycnt += rt;
        }
        int inc = mycnt;
        #pragma unroll
        for (int d = 1; d < 64; d <<= 1) {
            int t = __shfl_up(inc, d);
            if (l >= d) inc += t;
        }
        int base = 0;
        if (l == 63) base = atomicAdd(fragCnt, inc);
        base = __shfl(base, 63);
        int o = base + inc - mycnt;
        #pragma unroll
        for (int k = 0; k < 8; ++k) {
            if (isroot[k]) {
                int n = r * 16 + k * 2 + h;
                int slot = o++;
                if (slot < fragCap) {
                    F[slot] = slot;
                    fragImg[slot] = img;
                    fragSums[slot] = make_float2(si[n], su[n]);
                    ruf[n] = ~slot;
                } else ruf[n] = ~0;
            }
        }
    }
    WBAR();
    // ---- edges: L/R by row-pair, T/B one pixel per lane ----
    {
        int s = -1;
        if (h == 0) {
            if (m & 1u) { int v = ruf[r * 16]; s = (v < 0) ? ~v : ~ruf[v]; }
            edges[ebase + r] = s;
        } else {
            if (m >> 31) { int v = ruf[r * 16 + nrun - 1]; s = (v < 0) ? ~v : ~ruf[v]; }
            edges[ebase + 32 + r] = s;
        }
    }
    {
        int srcl = (l < 32) ? 0 : 62;      // lane holding full mask of row 0 / 31
        unsigned mm = __shfl(m, srcl);
        int x = l & 31;
        int s = -1;
        if ((mm >> x) & 1) {
            unsigned stt = mm & ~(mm << 1);
            int row = (l < 32) ? 0 : 31;
            int node = row * 16 + __popc(stt & ((2u << x) - 1)) - 1;
            int v = ruf[node];
            s = (v < 0) ? ~v : ~ruf[v];
        }
        edges[ebase + 64 + l] = s;
    }
}

// ============ phase B: boundary slot unions ============
__global__ void bound_k(const int* __restrict__ edges, int* __restrict__ F) {
    int img = blockIdx.x / 248;
    int e = (blockIdx.x % 248) * 256 + threadIdx.x;
    int sA, sB;
    if (e < 31744) {            // vertical boundary: tx=k <-> k+1, row y
        int k = e >> 10, y = e & 1023;
        int ty = y >> 5, rr = y & 31;
        int tileA = img * 1024 + ty * 32 + k;
        sA = edges[tileA * 128 + 32 + rr];
        sB = edges[(tileA + 1) * 128 + rr];
    } else {                    // horizontal boundary
        int e2 = e - 31744;
        int k = e2 >> 10, x = e2 & 1023;
        int tileA = img * 1024 + k * 32 + (x >> 5);
        sA = edges[tileA * 128 + 96 + (x & 31)];
        sB = edges[(tileA + 32) * 128 + 64 + (x & 31)];
    }
    if (sA >= 0 && sB >= 0) unite_f(F, sA, sB);
}

// ============ phase C: fold donor fragments into final roots ============
__global__ void merge_frag_k(int* __restrict__ F, float* __restrict__ fragSums,
                             const int* __restrict__ fragCnt, int fragCap) {
    int n = fragCnt[0]; if (n > fragCap) n = fragCap;
    for (int i = blockIdx.x * blockDim.x + threadIdx.x; i < n;
         i += gridDim.x * blockDim.x) {
        int rt = find_f(F, i);
        if (rt != i) {
            float2 d = ((const float2*)fragSums)[i];
            unsafeAtomicAdd(&fragSums[2 * rt], d.x);
            unsafeAtomicAdd(&fragSums[2 * rt + 1], d.y);
        }
    }
}

// ============ phase D: dice over final roots, block partials ============
__global__ void dice_frag_k(const int* __restrict__ F, const int* __restrict__ fragImg,
                            const float2* __restrict__ fragSums,
                            const int* __restrict__ fragCnt,
                            float* __restrict__ partials, int b0, int B, int fragCap) {
    __shared__ float sb[8][2];
    if (threadIdx.x < 16) ((float*)sb)[threadIdx.x] = 0.f;
    __syncthreads();
    int n = fragCnt[0]; if (n > fragCap) n = fragCap;
    for (int i = blockIdx.x * blockDim.x + threadIdx.x; i < n;
         i += gridDim.x * blockDim.x) {
        if (F[i] != i) continue;
        float2 s2 = fragSums[i];
        float d = (2.f * s2.x + 1e-6f) / (s2.y + 1e-6f);
        int ci = fragImg[i];
        atomicAdd(&sb[ci][0], d);
        atomicAdd(&sb[ci][1], 1.f);
    }
    __syncthreads();
    if (threadIdx.x < 16) {
        int ci = threadIdx.x >> 1, j = threadIdx.x & 1;
        int imgg = b0 + ci;
        if (imgg < B)
            partials[(blockIdx.x * B + imgg) * 2 + j] += ((float*)sb)[threadIdx.x];
    }
}

__global__ void zero_partials_k(float* __restrict__ p, int n, int* __restrict__ fragCnt) {
    int i = blockIdx.x * blockDim.x + threadIdx.x;
    if (i < n) p[i] = 0.f;
    if (i == 0) fragCnt[0] = 0;
}
__global__ void zero_frag_k(int* __restrict__ fragCnt) {
    if (threadIdx.x == 0) fragCnt[0] = 0;
}

__global__ void final_k(const float* __restrict__ partials, float* __restrict__ out, int B) {
    __shared__ float sb[128][2];
    int t = threadIdx.x;
    if (t < 2 * B) {
        int img = t >> 1, j = t & 1;
        float a = 0.f;
        for (int bkt = 0; bkt < NB_FRAG; ++bkt) a += partials[(bkt * B + img) * 2 + j];
        sb[img][j] = a;
    }
    __syncthreads();
    if (t == 0) {
        float acc = 0.f;
        for (int img = 0; img < B; ++img) {
            float s = sb[img][0], nn = sb[img][1];
            acc += (nn > 0.f) ? (1.f - s / nn) : 1.f;
        }
        out[0] = acc / (float)B;
    }
}

// ============ launch ============
extern "C" void kernel_launch(void* const* d_in, const int* in_sizes, int n_in,
                              void* d_out, int out_size, void* d_ws, size_t ws_size,
                              hipStream_t stream) {
    const float* pred = (const float*)d_in[0];
    const float* targ = (const float*)d_in[1];
    float* out = (float*)d_out;
    int B = in_sizes[0] / NPIX;
    if (B < 1) B = 1;

    char* ws = (char*)d_ws;
    size_t off = 0;
    float* partials = (float*)ws;
    off += ((size_t)NB_FRAG * B * 2 * sizeof(float) + 255) & ~(size_t)255;
    int* fragCnt = (int*)(ws + off);
    off += 256;
    size_t fixed = off;

    const size_t perImg = (size_t)1024 * 128 * 4 + (size_t)FRAG_PER_IMG * 4
                        + (size_t)FRAG_PER_IMG * 4 + (size_t)FRAG_PER_IMG * 8;
    int maxC = 1;
    if (ws_size > fixed + perImg) {
        size_t mm = (ws_size - fixed) / perImg;
        maxC = (int)(mm < (size_t)B ? mm : (size_t)B);
        if (maxC < 1) maxC = 1;
        if (maxC > 8) maxC = 8;
    }
    int*    edgesA   = (int*)   (ws + off); off += (size_t)maxC * 1024 * 128 * 4;
    int*    F        = (int*)   (ws + off); off += (size_t)maxC * FRAG_PER_IMG * 4;
    int*    fragImg  = (int*)   (ws + off); off += (size_t)maxC * FRAG_PER_IMG * 4;
    float2* fragSums = (float2*)(ws + off);

    zero_partials_k<<<(NB_FRAG * B * 2 + 255) / 256, 256, 0, stream>>>(
        partials, NB_FRAG * B * 2, fragCnt);

    for (int b0 = 0; b0 < B; b0 += maxC) {
        int C = (B - b0 < maxC) ? (B - b0) : maxC;
        const float* pc = pred + (size_t)b0 * NPIX;
        const float* tc = targ + (size_t)b0 * NPIX;
        int fragCap = C * FRAG_PER_IMG;
        int nwg = C * 256;
        if (b0 > 0) zero_frag_k<<<1, 64, 0, stream>>>(fragCnt);
        local_k<<<nwg, 256, 0, stream>>>((const float4*)pc, (const float4*)tc,
                                         edgesA, F, fragImg, fragSums, fragCnt,
                                         fragCap, nwg);
        bound_k<<<C * 248, 256, 0, stream>>>(edgesA, F);
        merge_frag_k<<<128, 256, 0, stream>>>(F, (float*)fragSums, fragCnt, fragCap);
        dice_frag_k<<<NB_FRAG, 256, 0, stream>>>(F, fragImg, fragSums, fragCnt,
                                                 partials, b0, B, fragCap);
    }

    final_k<<<1, 256, 0, stream>>>(partials, out, B);
}

// Round 9
// 133.950 us; speedup vs baseline: 1.2413x; 1.1218x over previous
//
#include <hip/hip_runtime.h>
#include <hip/hip_bf16.h>

#define NPIX (1 << 20)
#define HDIM 1024
#define NREG 64          // distributed slot-allocator counters
#define REGCAP 8192      // slots per region (power of 2)
#define NB_FRAG 64

#define WBAR() __builtin_amdgcn_wave_barrier()

// ============ slot-level union-find (global, union-by-min) ============
__device__ __forceinline__ int find_f(int* F, int x) {
    for (;;) {
        int p = F[x];
        if (p == x) return x;
        int gp = F[p];
        if (gp == p) return p;
        F[x] = gp;   // path halving, benign race
        x = gp;
    }
}
__device__ __forceinline__ void unite_f(int* F, int a, int b) {
    a = find_f(F, a); b = find_f(F, b);
    while (a != b) {
        if (a < b) { int t = a; a = b; b = t; }
        int old = atomicCAS(&F[a], a, b);
        if (old == a) return;
        a = find_f(F, old); b = find_f(F, b);
    }
}

// ============ LDS union-find over run nodes (id = row*16 + k) ============
__device__ __forceinline__ int find_r(int* R, int n) {
    int p = R[n];
    while (p != n) {
        int gp = R[p];
        if (gp == p) return p;
        R[n] = gp;
        n = gp;
        p = R[n];
    }
    return n;
}
__device__ __forceinline__ void unite_r(int* R, int a, int b) {
    a = find_r(R, a); b = find_r(R, b);
    while (a != b) {
        if (a < b) { int t = a; a = b; b = t; }
        int old = atomicCAS(&R[a], a, b);
        if (old == a) return;
        a = find_r(R, old); b = find_r(R, b);
    }
}

// ============ phase A: 4 tiles/block, one tile per WAVE, interleaved ======
__global__ __launch_bounds__(256) void local_k(
        const float4* __restrict__ pred4, const float4* __restrict__ targ4,
        int* __restrict__ edges, int* __restrict__ F,
        int* __restrict__ fragImg, float2* __restrict__ fragSums,
        int* __restrict__ fragCnt, int nwg) {
    int wid = threadIdx.x >> 6;
    int l   = threadIdx.x & 63;
    int tile = wid * nwg + blockIdx.x;     // interleaved: block mixes 4 distant tiles
    int img = tile >> 10;
    int ty = (tile >> 5) & 31, tx = tile & 31;
    int r = l >> 1, h = l & 1;

    __shared__ int s_ruf[4][512];
    __shared__ float s_i[4][512], s_u[4][512];
    int*   ruf = &s_ruf[wid][0];
    float* si  = &s_i[wid][0];
    float* su  = &s_u[wid][0];

    int rowg = img * HDIM + ty * 32 + r;
    int qb = rowg * 256 + tx * 8 + h * 4;
    int ebase = tile * 128;

    float sv[16], iv[16];
    unsigned hm = 0;
    #pragma unroll
    for (int q = 0; q < 4; ++q) {
        float4 P4 = pred4[qb + q];
        float4 T4 = targ4[qb + q];
        float s0 = P4.x + T4.x, s1 = P4.y + T4.y, s2 = P4.z + T4.z, s3 = P4.w + T4.w;
        sv[q*4+0] = s0; sv[q*4+1] = s1; sv[q*4+2] = s2; sv[q*4+3] = s3;
        iv[q*4+0] = P4.x * T4.x; iv[q*4+1] = P4.y * T4.y;
        iv[q*4+2] = P4.z * T4.z; iv[q*4+3] = P4.w * T4.w;
        if (s0 > 0.f) hm |= 1u << (q*4+0);
        if (s1 > 0.f) hm |= 1u << (q*4+1);
        if (s2 > 0.f) hm |= 1u << (q*4+2);
        if (s3 > 0.f) hm |= 1u << (q*4+3);
    }
    unsigned m = hm << (h * 16);
    m |= __shfl_xor(m, 1);                 // full 32-bit row mask on both lanes
    unsigned st = m & ~(m << 1);           // run starts
    int nrun = __popc(st);

    if (__ballot(m != 0) == 0ull) {        // empty tile: -1 edges, 2 stores/lane
        edges[ebase + l] = -1;             // L(0..31) | R(32..63)
        edges[ebase + 64 + l] = -1;        // T(64..95) | B(96..127)
        return;
    }

    #pragma unroll
    for (int k = 0; k < 8; ++k) ruf[l * 8 + k] = l * 8 + k;

    // ---- P3a: per-run sums; straddler partial passed in registers ----
    int nrun0 = __popc(st & 0xFFFFu);
    bool strad = ((m >> 15) & 1) && ((m >> 16) & 1);
    float ai = 0.f, au = 0.f, fi = 0.f, fu = 0.f;
    int rid = h ? (nrun0 - 1) : -1;
    bool in = false;
    #pragma unroll
    for (int j = 0; j < 16; ++j) {
        if ((hm >> j) & 1) {
            int x = h * 16 + j;
            if ((st >> x) & 1) {
                if (in) { si[r*16+rid] = ai; su[r*16+rid] = au; }
                ++rid; ai = 0.f; au = 0.f; in = true;
            }
            if (in) { ai += iv[j]; au += sv[j]; }
            else    { fi += iv[j]; fu += sv[j]; }   // leading continuation (h=1)
        }
    }
    float gi = __shfl_xor(fi, 1), gu = __shfl_xor(fu, 1);
    if (in) {
        if (h == 0 && strad) { ai += gi; au += gu; }
        si[r*16+rid] = ai; su[r*16+rid] = au;
    }
    WBAR();
    // ---- P4: vertical run unions, lane pair per row boundary ----
    {
        int bsrc = (l & ~1) + 2; if (bsrc > 63) bsrc = 63;
        unsigned mb = __shfl(m, bsrc);
        if (l < 62) {
            unsigned stb = mb & ~(mb << 1);
            unsigned o = m & mb;
            unsigned os = o & ~(o << 1);
            os &= h ? 0xFFFF0000u : 0x0000FFFFu;
            while (os) {
                int x = __ffs(os) - 1; os &= os - 1;
                unsigned below = (2u << x) - 1;
                unite_r(ruf, r * 16 + __popc(st & below) - 1,
                             (r + 1) * 16 + __popc(stb & below) - 1);
            }
        }
    }
    WBAR();
    // ---- P5: flatten + fold sums into roots (nodes interleaved across pair) ----
    int root8[8]; bool valid8[8];
    #pragma unroll
    for (int k = 0; k < 8; ++k) {
        int ridx = k * 2 + h;
        int n = r * 16 + ridx;
        bool v = ridx < nrun;
        valid8[k] = v; root8[k] = n;
        if (v) {
            int root = find_r(ruf, n);
            root8[k] = root;
            if (root != n) {
                float a = si[n], b = su[n];
                ruf[n] = root;
                atomicAdd(&si[root], a);
                atomicAdd(&su[root], b);
            }
        }
    }
    WBAR();
    // ---- P7: slot alloc via DISTRIBUTED counter (region = tile & 63) ----
    {
        bool isroot[8]; int mycnt = 0;
        #pragma unroll
        for (int k = 0; k < 8; ++k) {
            int n = r * 16 + k * 2 + h;
            bool rt = valid8[k] && (root8[k] == n);
            isroot[k] = rt; mycnt += rt;
        }
        int inc = mycnt;
        #pragma unroll
        for (int d = 1; d < 64; d <<= 1) {
            int t = __shfl_up(inc, d);
            if (l >= d) inc += t;
        }
        int cidx = tile & (NREG - 1);
        int base = 0;
        if (l == 63) base = atomicAdd(&fragCnt[cidx], inc);
        base = __shfl(base, 63);
        int o = base + inc - mycnt;
        #pragma unroll
        for (int k = 0; k < 8; ++k) {
            if (isroot[k]) {
                int n = r * 16 + k * 2 + h;
                int off = o++;
                if (off < REGCAP) {
                    int slot = cidx * REGCAP + off;
                    F[slot] = slot;
                    fragImg[slot] = img;
                    fragSums[slot] = make_float2(si[n], su[n]);
                    ruf[n] = ~slot;
                } else ruf[n] = ~0;
            }
        }
    }
    WBAR();
    // ---- edges: L/R by row-pair, T/B one pixel per lane ----
    {
        int s = -1;
        if (h == 0) {
            if (m & 1u) { int v = ruf[r * 16]; s = (v < 0) ? ~v : ~ruf[v]; }
            edges[ebase + r] = s;
        } else {
            if (m >> 31) { int v = ruf[r * 16 + nrun - 1]; s = (v < 0) ? ~v : ~ruf[v]; }
            edges[ebase + 32 + r] = s;
        }
    }
    {
        int srcl = (l < 32) ? 0 : 62;      // lane holding full mask of row 0 / 31
        unsigned mm = __shfl(m, srcl);
        int x = l & 31;
        int s = -1;
        if ((mm >> x) & 1) {
            unsigned stt = mm & ~(mm << 1);
            int row = (l < 32) ? 0 : 31;
            int node = row * 16 + __popc(stt & ((2u << x) - 1)) - 1;
            int v = ruf[node];
            s = (v < 0) ? ~v : ~ruf[v];
        }
        edges[ebase + 64 + l] = s;
    }
}

// ============ phase B: boundary slot unions ============
__global__ void bound_k(const int* __restrict__ edges, int* __restrict__ F) {
    int img = blockIdx.x / 248;
    int e = (blockIdx.x % 248) * 256 + threadIdx.x;
    int sA, sB;
    if (e < 31744) {            // vertical boundary: tx=k <-> k+1, row y
        int k = e >> 10, y = e & 1023;
        int ty = y >> 5, rr = y & 31;
        int tileA = img * 1024 + ty * 32 + k;
        sA = edges[tileA * 128 + 32 + rr];
        sB = edges[(tileA + 1) * 128 + rr];
    } else {                    // horizontal boundary
        int e2 = e - 31744;
        int k = e2 >> 10, x = e2 & 1023;
        int tileA = img * 1024 + k * 32 + (x >> 5);
        sA = edges[tileA * 128 + 96 + (x & 31)];
        sB = edges[(tileA + 32) * 128 + 64 + (x & 31)];
    }
    if (sA >= 0 && sB >= 0) unite_f(F, sA, sB);
}

// ============ phase C: fold donor fragments into final roots ============
__global__ void merge_frag_k(int* __restrict__ F, float* __restrict__ fragSums,
                             const int* __restrict__ fragCnt) {
    int total = NREG * REGCAP;
    for (int i = blockIdx.x * blockDim.x + threadIdx.x; i < total;
         i += gridDim.x * blockDim.x) {
        int cidx = i / REGCAP, off = i & (REGCAP - 1);
        int cnt = fragCnt[cidx]; if (cnt > REGCAP) cnt = REGCAP;
        if (off >= cnt) continue;
        int rt = find_f(F, i);
        if (rt != i) {
            float2 d = ((const float2*)fragSums)[i];
            unsafeAtomicAdd(&fragSums[2 * rt], d.x);
            unsafeAtomicAdd(&fragSums[2 * rt + 1], d.y);
        }
    }
}

// ============ phase D: dice over final roots, block partials ============
__global__ void dice_frag_k(const int* __restrict__ F, const int* __restrict__ fragImg,
                            const float2* __restrict__ fragSums,
                            const int* __restrict__ fragCnt,
                            float* __restrict__ partials, int b0, int B) {
    __shared__ float sb[8][2];
    if (threadIdx.x < 16) ((float*)sb)[threadIdx.x] = 0.f;
    __syncthreads();
    int total = NREG * REGCAP;
    for (int i = blockIdx.x * blockDim.x + threadIdx.x; i < total;
         i += gridDim.x * blockDim.x) {
        int cidx = i / REGCAP, off = i & (REGCAP - 1);
        int cnt = fragCnt[cidx]; if (cnt > REGCAP) cnt = REGCAP;
        if (off >= cnt) continue;
        if (F[i] != i) continue;             // not a final root
        float2 s2 = fragSums[i];
        float d = (2.f * s2.x + 1e-6f) / (s2.y + 1e-6f);
        int ci = fragImg[i];
        atomicAdd(&sb[ci][0], d);
        atomicAdd(&sb[ci][1], 1.f);
    }
    __syncthreads();
    if (threadIdx.x < 16) {
        int ci = threadIdx.x >> 1, j = threadIdx.x & 1;
        int imgg = b0 + ci;
        if (imgg < B)
            partials[(blockIdx.x * B + imgg) * 2 + j] += ((float*)sb)[threadIdx.x];
    }
}

__global__ void zero_partials_k(float* __restrict__ p, int n, int* __restrict__ fragCnt) {
    int i = blockIdx.x * blockDim.x + threadIdx.x;
    if (i < n) p[i] = 0.f;
    if (i < NREG) fragCnt[i] = 0;
}
__global__ void zero_frag_k(int* __restrict__ fragCnt) {
    if (threadIdx.x < NREG) fragCnt[threadIdx.x] = 0;
}

__global__ void final_k(const float* __restrict__ partials, float* __restrict__ out, int B) {
    __shared__ float sb[128][2];
    int t = threadIdx.x;
    if (t < 2 * B) {
        int img = t >> 1, j = t & 1;
        float a = 0.f;
        for (int bkt = 0; bkt < NB_FRAG; ++bkt) a += partials[(bkt * B + img) * 2 + j];
        sb[img][j] = a;
    }
    __syncthreads();
    if (t == 0) {
        float acc = 0.f;
        for (int img = 0; img < B; ++img) {
            float s = sb[img][0], nn = sb[img][1];
            acc += (nn > 0.f) ? (1.f - s / nn) : 1.f;
        }
        out[0] = acc / (float)B;
    }
}

// ============ launch ============
extern "C" void kernel_launch(void* const* d_in, const int* in_sizes, int n_in,
                              void* d_out, int out_size, void* d_ws, size_t ws_size,
                              hipStream_t stream) {
    const float* pred = (const float*)d_in[0];
    const float* targ = (const float*)d_in[1];
    float* out = (float*)d_out;
    int B = in_sizes[0] / NPIX;
    if (B < 1) B = 1;

    char* ws = (char*)d_ws;
    size_t off = 0;
    float* partials = (float*)ws;
    off += ((size_t)NB_FRAG * B * 2 * sizeof(float) + 255) & ~(size_t)255;
    int* fragCnt = (int*)(ws + off);
    off += ((size_t)NREG * 4 + 255) & ~(size_t)255;

    // fixed slot pool: F 2MB + fragImg 2MB + fragSums 4MB
    const size_t NSLOT = (size_t)NREG * REGCAP;
    int*    F        = (int*)   (ws + off); off += NSLOT * 4;
    int*    fragImg  = (int*)   (ws + off); off += NSLOT * 4;
    float2* fragSums = (float2*)(ws + off); off += NSLOT * 8;
    size_t fixed = off;

    const size_t perImg = (size_t)1024 * 128 * 4;   // edges only
    int maxC = 1;
    if (ws_size > fixed + perImg) {
        size_t mm = (ws_size - fixed) / perImg;
        maxC = (int)(mm < (size_t)B ? mm : (size_t)B);
        if (maxC < 1) maxC = 1;
        if (maxC > 8) maxC = 8;
    }
    int* edgesA = (int*)(ws + off);

    zero_partials_k<<<(NB_FRAG * B * 2 + 255) / 256, 256, 0, stream>>>(
        partials, NB_FRAG * B * 2, fragCnt);

    for (int b0 = 0; b0 < B; b0 += maxC) {
        int C = (B - b0 < maxC) ? (B - b0) : maxC;
        const float* pc = pred + (size_t)b0 * NPIX;
        const float* tc = targ + (size_t)b0 * NPIX;
        int nwg = C * 256;
        if (b0 > 0) zero_frag_k<<<1, 64, 0, stream>>>(fragCnt);
        local_k<<<nwg, 256, 0, stream>>>((const float4*)pc, (const float4*)tc,
                                         edgesA, F, fragImg, fragSums, fragCnt, nwg);
        bound_k<<<C * 248, 256, 0, stream>>>(edgesA, F);
        merge_frag_k<<<128, 256, 0, stream>>>(F, (float*)fragSums, fragCnt);
        dice_frag_k<<<NB_FRAG, 256, 0, stream>>>(F, fragImg, fragSums, fragCnt,
                                                 partials, b0, B);
    }

    final_k<<<1, 256, 0, stream>>>(partials, out, B);
}

// Round 10
// 105.722 us; speedup vs baseline: 1.5728x; 1.2670x over previous
//
#include <hip/hip_runtime.h>
#include <hip/hip_bf16.h>

#define NPIX (1 << 20)
#define HDIM 1024
#define NREG 64          // regions: img*8 + (tile&7)
#define REGCAP 4096      // slots per region

#define WBAR() __builtin_amdgcn_wave_barrier()

// ============ slot-level union-find (global, union-by-min) ============
__device__ __forceinline__ int find_f(int* F, int x) {
    for (;;) {
        int p = F[x];
        if (p == x) return x;
        int gp = F[p];
        if (gp == p) return p;
        F[x] = gp;   // path halving, benign race
        x = gp;
    }
}
__device__ __forceinline__ void unite_f(int* F, int a, int b) {
    a = find_f(F, a); b = find_f(F, b);
    while (a != b) {
        if (a < b) { int t = a; a = b; b = t; }
        int old = atomicCAS(&F[a], a, b);
        if (old == a) return;
        a = find_f(F, old); b = find_f(F, b);
    }
}

// ============ LDS union-find over run nodes (id = row*16 + k) ============
__device__ __forceinline__ int find_r(int* R, int n) {
    int p = R[n];
    while (p != n) {
        int gp = R[p];
        if (gp == p) return p;
        R[n] = gp;
        n = gp;
        p = R[n];
    }
    return n;
}
__device__ __forceinline__ void unite_r(int* R, int a, int b) {
    a = find_r(R, a); b = find_r(R, b);
    while (a != b) {
        if (a < b) { int t = a; a = b; b = t; }
        int old = atomicCAS(&R[a], a, b);
        if (old == a) return;
        a = find_r(R, old); b = find_r(R, b);
    }
}

// ============ phase A: 4 tiles/block, one tile per WAVE, interleaved ======
__global__ __launch_bounds__(256) void local_k(
        const float4* __restrict__ pred4, const float4* __restrict__ targ4,
        int* __restrict__ edges, int* __restrict__ F,
        float2* __restrict__ fragSums,
        int* __restrict__ fragCnt, int nwg) {
    int wid = threadIdx.x >> 6;
    int l   = threadIdx.x & 63;
    int tile = wid * nwg + blockIdx.x;     // interleaved: block mixes 4 distant tiles
    int img = tile >> 10;
    int ty = (tile >> 5) & 31, tx = tile & 31;
    int r = l >> 1, h = l & 1;

    __shared__ int s_ruf[4][512];
    __shared__ float s_i[4][512], s_u[4][512];
    int*   ruf = &s_ruf[wid][0];
    float* si  = &s_i[wid][0];
    float* su  = &s_u[wid][0];

    int rowg = img * HDIM + ty * 32 + r;
    int qb = rowg * 256 + tx * 8 + h * 4;
    int ebase = tile * 128;

    float sv[16], iv[16];
    unsigned hm = 0;
    #pragma unroll
    for (int q = 0; q < 4; ++q) {
        float4 P4 = pred4[qb + q];
        float4 T4 = targ4[qb + q];
        float s0 = P4.x + T4.x, s1 = P4.y + T4.y, s2 = P4.z + T4.z, s3 = P4.w + T4.w;
        sv[q*4+0] = s0; sv[q*4+1] = s1; sv[q*4+2] = s2; sv[q*4+3] = s3;
        iv[q*4+0] = P4.x * T4.x; iv[q*4+1] = P4.y * T4.y;
        iv[q*4+2] = P4.z * T4.z; iv[q*4+3] = P4.w * T4.w;
        if (s0 > 0.f) hm |= 1u << (q*4+0);
        if (s1 > 0.f) hm |= 1u << (q*4+1);
        if (s2 > 0.f) hm |= 1u << (q*4+2);
        if (s3 > 0.f) hm |= 1u << (q*4+3);
    }
    unsigned m = hm << (h * 16);
    m |= __shfl_xor(m, 1);                 // full 32-bit row mask on both lanes
    unsigned st = m & ~(m << 1);           // run starts
    int nrun = __popc(st);

    if (__ballot(m != 0) == 0ull) {        // empty tile: -1 edges, 2 stores/lane
        edges[ebase + l] = -1;             // L(0..31) | R(32..63)
        edges[ebase + 64 + l] = -1;        // T(64..95) | B(96..127)
        return;
    }

    #pragma unroll
    for (int k = 0; k < 8; ++k) ruf[l * 8 + k] = l * 8 + k;

    // ---- P3a: per-run sums; straddler partial passed in registers ----
    int nrun0 = __popc(st & 0xFFFFu);
    bool strad = ((m >> 15) & 1) && ((m >> 16) & 1);
    float ai = 0.f, au = 0.f, fi = 0.f, fu = 0.f;
    int rid = h ? (nrun0 - 1) : -1;
    bool in = false;
    #pragma unroll
    for (int j = 0; j < 16; ++j) {
        if ((hm >> j) & 1) {
            int x = h * 16 + j;
            if ((st >> x) & 1) {
                if (in) { si[r*16+rid] = ai; su[r*16+rid] = au; }
                ++rid; ai = 0.f; au = 0.f; in = true;
            }
            if (in) { ai += iv[j]; au += sv[j]; }
            else    { fi += iv[j]; fu += sv[j]; }   // leading continuation (h=1)
        }
    }
    float gi = __shfl_xor(fi, 1), gu = __shfl_xor(fu, 1);
    if (in) {
        if (h == 0 && strad) { ai += gi; au += gu; }
        si[r*16+rid] = ai; su[r*16+rid] = au;
    }
    WBAR();
    // ---- P4: vertical run unions, lane pair per row boundary ----
    {
        int bsrc = (l & ~1) + 2; if (bsrc > 63) bsrc = 63;
        unsigned mb = __shfl(m, bsrc);
        if (l < 62) {
            unsigned stb = mb & ~(mb << 1);
            unsigned o = m & mb;
            unsigned os = o & ~(o << 1);
            os &= h ? 0xFFFF0000u : 0x0000FFFFu;
            while (os) {
                int x = __ffs(os) - 1; os &= os - 1;
                unsigned below = (2u << x) - 1;
                unite_r(ruf, r * 16 + __popc(st & below) - 1,
                             (r + 1) * 16 + __popc(stb & below) - 1);
            }
        }
    }
    WBAR();
    // ---- P5: flatten + fold sums into roots (nodes interleaved across pair) ----
    int root8[8]; bool valid8[8];
    #pragma unroll
    for (int k = 0; k < 8; ++k) {
        int ridx = k * 2 + h;
        int n = r * 16 + ridx;
        bool v = ridx < nrun;
        valid8[k] = v; root8[k] = n;
        if (v) {
            int root = find_r(ruf, n);
            root8[k] = root;
            if (root != n) {
                float a = si[n], b = su[n];
                ruf[n] = root;
                atomicAdd(&si[root], a);
                atomicAdd(&su[root], b);
            }
        }
    }
    WBAR();
    // ---- P7: slot alloc via distributed counter; region encodes image ----
    {
        bool isroot[8]; int mycnt = 0;
        #pragma unroll
        for (int k = 0; k < 8; ++k) {
            int n = r * 16 + k * 2 + h;
            bool rt = valid8[k] && (root8[k] == n);
            isroot[k] = rt; mycnt += rt;
        }
        int inc = mycnt;
        #pragma unroll
        for (int d = 1; d < 64; d <<= 1) {
            int t = __shfl_up(inc, d);
            if (l >= d) inc += t;
        }
        int cidx = (img << 3) | (tile & 7);
        int base = 0;
        if (l == 63) base = atomicAdd(&fragCnt[cidx], inc);
        base = __shfl(base, 63);
        int o = base + inc - mycnt;
        #pragma unroll
        for (int k = 0; k < 8; ++k) {
            if (isroot[k]) {
                int n = r * 16 + k * 2 + h;
                int off = o++;
                if (off < REGCAP) {
                    int slot = cidx * REGCAP + off;
                    F[slot] = slot;
                    fragSums[slot] = make_float2(si[n], su[n]);
                    ruf[n] = ~slot;
                } else ruf[n] = ~0;
            }
        }
    }
    WBAR();
    // ---- edges: L/R by row-pair, T/B one pixel per lane ----
    {
        int s = -1;
        if (h == 0) {
            if (m & 1u) { int v = ruf[r * 16]; s = (v < 0) ? ~v : ~ruf[v]; }
            edges[ebase + r] = s;
        } else {
            if (m >> 31) { int v = ruf[r * 16 + nrun - 1]; s = (v < 0) ? ~v : ~ruf[v]; }
            edges[ebase + 32 + r] = s;
        }
    }
    {
        int srcl = (l < 32) ? 0 : 62;      // lane holding full mask of row 0 / 31
        unsigned mm = __shfl(m, srcl);
        int x = l & 31;
        int s = -1;
        if ((mm >> x) & 1) {
            unsigned stt = mm & ~(mm << 1);
            int row = (l < 32) ? 0 : 31;
            int node = row * 16 + __popc(stt & ((2u << x) - 1)) - 1;
            int v = ruf[node];
            s = (v < 0) ? ~v : ~ruf[v];
        }
        edges[ebase + 64 + l] = s;
    }
}

// ============ phase B: boundary slot unions ============
__global__ void bound_k(const int* __restrict__ edges, int* __restrict__ F) {
    int img = blockIdx.x / 248;
    int e = (blockIdx.x % 248) * 256 + threadIdx.x;
    int sA, sB;
    if (e < 31744) {            // vertical boundary: tx=k <-> k+1, row y
        int k = e >> 10, y = e & 1023;
        int ty = y >> 5, rr = y & 31;
        int tileA = img * 1024 + ty * 32 + k;
        sA = edges[tileA * 128 + 32 + rr];
        sB = edges[(tileA + 1) * 128 + rr];
    } else {                    // horizontal boundary
        int e2 = e - 31744;
        int k = e2 >> 10, x = e2 & 1023;
        int tileA = img * 1024 + k * 32 + (x >> 5);
        sA = edges[tileA * 128 + 96 + (x & 31)];
        sB = edges[(tileA + 32) * 128 + 64 + (x & 31)];
    }
    if (sA >= 0 && sB >= 0) unite_f(F, sA, sB);
}

// ============ phase C: fold donor fragments into final roots ============
__global__ void merge_frag_k(int* __restrict__ F, float* __restrict__ fragSums,
                             const int* __restrict__ fragCnt, int C) {
    int cidx = blockIdx.x;
    if (cidx >= C * 8) return;
    int cnt = fragCnt[cidx]; if (cnt > REGCAP) cnt = REGCAP;
    for (int off = threadIdx.x; off < cnt; off += 256) {
        int i = cidx * REGCAP + off;
        int rt = find_f(F, i);
        if (rt != i) {
            float2 d = ((const float2*)fragSums)[i];
            unsafeAtomicAdd(&fragSums[2 * rt], d.x);
            unsafeAtomicAdd(&fragSums[2 * rt + 1], d.y);
        }
    }
}

// ============ phase D: dice per region (one image per region) ============
__global__ void dice_frag_k(const int* __restrict__ F, const float2* __restrict__ fragSums,
                            const int* __restrict__ fragCnt,
                            float* __restrict__ partials, int b0, int C) {
    int cidx = blockIdx.x;
    if (cidx >= C * 8) return;
    int cnt = fragCnt[cidx]; if (cnt > REGCAP) cnt = REGCAP;
    float ds = 0.f, dn = 0.f;
    for (int off = threadIdx.x; off < cnt; off += 256) {
        int i = cidx * REGCAP + off;
        if (F[i] != i) continue;             // not a final root
        float2 s2 = fragSums[i];
        ds += (2.f * s2.x + 1e-6f) / (s2.y + 1e-6f);
        dn += 1.f;
    }
    #pragma unroll
    for (int d = 32; d > 0; d >>= 1) {
        ds += __shfl_down(ds, d);
        dn += __shfl_down(dn, d);
    }
    __shared__ float s_s[4], s_n[4];
    int wid = threadIdx.x >> 6;
    if ((threadIdx.x & 63) == 0) { s_s[wid] = ds; s_n[wid] = dn; }
    __syncthreads();
    if (threadIdx.x == 0) {
        float a = s_s[0] + s_s[1] + s_s[2] + s_s[3];
        float c = s_n[0] + s_n[1] + s_n[2] + s_n[3];
        int img = b0 + (cidx >> 3), sub = cidx & 7;
        partials[img * 16 + sub * 2]     += a;
        partials[img * 16 + sub * 2 + 1] += c;
    }
}

__global__ void zero_partials_k(float* __restrict__ p, int n, int* __restrict__ fragCnt) {
    int i = threadIdx.x;
    if (i < n) p[i] = 0.f;
    if (i < NREG) fragCnt[i] = 0;
}
__global__ void zero_frag_k(int* __restrict__ fragCnt) {
    if (threadIdx.x < NREG) fragCnt[threadIdx.x] = 0;
}

__global__ void final_k(const float* __restrict__ partials, float* __restrict__ out, int B) {
    if (threadIdx.x == 0 && blockIdx.x == 0) {
        float acc = 0.f;
        for (int img = 0; img < B; ++img) {
            float s = 0.f, n = 0.f;
            for (int sub = 0; sub < 8; ++sub) {
                s += partials[img * 16 + sub * 2];
                n += partials[img * 16 + sub * 2 + 1];
            }
            acc += (n > 0.f) ? (1.f - s / n) : 1.f;
        }
        out[0] = acc / (float)B;
    }
}

// ============ launch ============
extern "C" void kernel_launch(void* const* d_in, const int* in_sizes, int n_in,
                              void* d_out, int out_size, void* d_ws, size_t ws_size,
                              hipStream_t stream) {
    const float* pred = (const float*)d_in[0];
    const float* targ = (const float*)d_in[1];
    float* out = (float*)d_out;
    int B = in_sizes[0] / NPIX;
    if (B < 1) B = 1;

    char* ws = (char*)d_ws;
    size_t off = 0;
    float* partials = (float*)ws;                       // B*16 floats
    off += ((size_t)B * 16 * sizeof(float) + 255) & ~(size_t)255;
    int* fragCnt = (int*)(ws + off);
    off += ((size_t)NREG * 4 + 255) & ~(size_t)255;

    // fixed slot pool: F 1MB + fragSums 2MB
    const size_t NSLOT = (size_t)NREG * REGCAP;
    int*    F        = (int*)   (ws + off); off += NSLOT * 4;
    float2* fragSums = (float2*)(ws + off); off += NSLOT * 8;
    size_t fixed = off;

    const size_t perImg = (size_t)1024 * 128 * 4;       // edges only (512KB)
    int maxC = 1;
    if (ws_size > fixed + perImg) {
        size_t mm = (ws_size - fixed) / perImg;
        maxC = (int)(mm < (size_t)B ? mm : (size_t)B);
        if (maxC < 1) maxC = 1;
        if (maxC > 8) maxC = 8;
    }
    int* edgesA = (int*)(ws + off);

    zero_partials_k<<<1, 256, 0, stream>>>(partials, B * 16, fragCnt);

    for (int b0 = 0; b0 < B; b0 += maxC) {
        int C = (B - b0 < maxC) ? (B - b0) : maxC;
        const float* pc = pred + (size_t)b0 * NPIX;
        const float* tc = targ + (size_t)b0 * NPIX;
        int nwg = C * 256;
        if (b0 > 0) zero_frag_k<<<1, 64, 0, stream>>>(fragCnt);
        local_k<<<nwg, 256, 0, stream>>>((const float4*)pc, (const float4*)tc,
                                         edgesA, F, fragSums, fragCnt, nwg);
        bound_k<<<C * 248, 256, 0, stream>>>(edgesA, F);
        merge_frag_k<<<NREG, 256, 0, stream>>>(F, (float*)fragSums, fragCnt, C);
        dice_frag_k<<<NREG, 256, 0, stream>>>(F, fragSums, fragCnt, partials, b0, C);
    }

    final_k<<<1, 64, 0, stream>>>(partials, out, B);
}